// Round 5
// baseline (402.362 us; speedup 1.0000x reference)
//
#include <hip/hip_runtime.h>

typedef __bf16 bf16x8 __attribute__((ext_vector_type(8)));
typedef float f32x4 __attribute__((ext_vector_type(4)));
typedef unsigned short u16;
typedef u16 u16x4 __attribute__((ext_vector_type(4)));
typedef u16 u16x8 __attribute__((ext_vector_type(8)));
typedef float float4v __attribute__((ext_vector_type(4)));

__device__ __forceinline__ u16 f2bf(float f) {
    __bf16 b = (__bf16)f;
    return __builtin_bit_cast(unsigned short, b);
}
__device__ __forceinline__ float bf2f(u16 x) {
    __bf16 b = __builtin_bit_cast(__bf16, x);
    return (float)b;
}

__device__ __forceinline__ void gld16(const void* g, void* l) {
    __builtin_amdgcn_global_load_lds((const __attribute__((address_space(1))) void*)g,
                                     (__attribute__((address_space(3))) void*)l, 16, 0, 0);
}

// bijective XCD chunk swizzle (m204)
__device__ __forceinline__ int xcd_swz(int orig, int nwg) {
    const int q = nwg >> 3, r = nwg & 7;
    const int xcd = orig & 7, pos = orig >> 3;
    return (xcd < r ? xcd * (q + 1) : r * (q + 1) + (xcd - r) * q) + pos;
}

// ---------------------------------------------------------------------------
// Weight transpose + f32->bf16 cast:  W[K][N] f32  ->  WT[N][K] bf16
// ---------------------------------------------------------------------------
__global__ __launch_bounds__(256) void transpose_kernel(
    const float* __restrict__ W, u16* __restrict__ WT, int K, int N)
{
    __shared__ u16 tile[64][65];
    const int tx = threadIdx.x & 63, ty = threadIdx.x >> 6;
    const int n0 = blockIdx.x * 64, k0 = blockIdx.y * 64;
    #pragma unroll
    for (int i = ty; i < 64; i += 4)
        tile[i][tx] = f2bf(W[(size_t)(k0 + i) * N + n0 + tx]);
    __syncthreads();
    #pragma unroll
    for (int i = ty; i < 64; i += 4)
        WT[(size_t)(n0 + i) * K + k0 + tx] = tile[tx][i];
}

// ---------------------------------------------------------------------------
// LayerNorm: x f32 [3072][1280] -> out bf16
// ---------------------------------------------------------------------------
__global__ __launch_bounds__(256) void ln_kernel(
    const float* __restrict__ x, const float* __restrict__ sc,
    const float* __restrict__ bias, u16* __restrict__ out)
{
    const int row = blockIdx.x, t = threadIdx.x;
    const float* xr = x + (size_t)row * 1280;
    float v[5], s1 = 0.f, s2 = 0.f;
    #pragma unroll
    for (int i = 0; i < 5; i++) {
        v[i] = xr[t + i * 256];
        s1 += v[i];
        s2 += v[i] * v[i];
    }
    #pragma unroll
    for (int off = 32; off; off >>= 1) {
        s1 += __shfl_down(s1, off);
        s2 += __shfl_down(s2, off);
    }
    __shared__ float rA[4], rB[4];
    if ((t & 63) == 0) { rA[t >> 6] = s1; rB[t >> 6] = s2; }
    __syncthreads();
    s1 = rA[0] + rA[1] + rA[2] + rA[3];
    s2 = rB[0] + rB[1] + rB[2] + rB[3];
    const float mu = s1 * (1.f / 1280.f);
    const float var = s2 * (1.f / 1280.f) - mu * mu;
    const float rstd = rsqrtf(var + 1e-6f);
    #pragma unroll
    for (int i = 0; i < 5; i++) {
        const int d = t + i * 256;
        out[(size_t)row * 1280 + d] = f2bf((v[i] - mu) * rstd * sc[d] + bias[d]);
    }
}

// ---------------------------------------------------------------------------
// Generic bf16 MFMA GEMM: C = A[M][K] @ BT[N][K]^T (+bias/res/gelu when SPLIT==1)
// 128x128 tile, BK=64, 4 waves, global_load_lds + XOR swizzle, XCD swizzle.
// SPLIT>1: blockIdx.z = K-slice; raw partial f32 -> outF + z*M*N (no bias).
// ---------------------------------------------------------------------------
template <int GELU, int RES, int OUTF, int OUTB, int SPLIT>
__global__ __launch_bounds__(256) void gemm_kernel(
    const u16* __restrict__ A, const u16* __restrict__ BT,
    const float* __restrict__ bias, const float* __restrict__ res,
    float* __restrict__ outF, u16* __restrict__ outB,
    int M, int N, int K)
{
    __shared__ u16 As[128 * 64];   // [row][64 bf16], 128B rows
    __shared__ u16 Bs[128 * 64];
    const int tid = threadIdx.x, lane = tid & 63, wave = tid >> 6;
    const int nwg = gridDim.x * gridDim.y;
    const int bid = xcd_swz(blockIdx.y * gridDim.x + blockIdx.x, nwg);
    const int m0 = (bid / gridDim.x) * 128, n0 = (bid % gridDim.x) * 128;
    const int wm = (wave >> 1) * 64, wn = (wave & 1) * 64;
    const int lr = lane & 15, lh = lane >> 4;
    const int srow = lane >> 3;
    const int schunk = (lane & 7) ^ (srow & 7);

    const int kchunk = K / SPLIT;
    const int kz = (SPLIT > 1) ? blockIdx.z : 0;
    const int kbeg = kz * kchunk, kend = kbeg + kchunk;

    f32x4 acc[4][4] = {};

    for (int k0 = kbeg; k0 < kend; k0 += 64) {
        #pragma unroll
        for (int s = 0; s < 4; s++) {
            const int seg = wave + s * 4;          // 0..15
            const int row = seg * 8 + srow;        // 0..127
            gld16(A + (size_t)(m0 + row) * K + k0 + schunk * 8, &As[seg * 512]);
            gld16(BT + (size_t)(n0 + row) * K + k0 + schunk * 8, &Bs[seg * 512]);
        }
        asm volatile("s_waitcnt vmcnt(0)" ::: "memory");
        __syncthreads();

        bf16x8 af[4][2], bfr[4][2];
        #pragma unroll
        for (int mi = 0; mi < 4; mi++) {
            const int row = wm + mi * 16 + lr;
            #pragma unroll
            for (int kk = 0; kk < 2; kk++) {
                const int cb = (kk * 64 + lh * 16) ^ ((row & 7) << 4);
                af[mi][kk] = *reinterpret_cast<const bf16x8*>((const char*)As + row * 128 + cb);
            }
        }
        #pragma unroll
        for (int ni = 0; ni < 4; ni++) {
            const int row = wn + ni * 16 + lr;
            #pragma unroll
            for (int kk = 0; kk < 2; kk++) {
                const int cb = (kk * 64 + lh * 16) ^ ((row & 7) << 4);
                bfr[ni][kk] = *reinterpret_cast<const bf16x8*>((const char*)Bs + row * 128 + cb);
            }
        }
        #pragma unroll
        for (int kk = 0; kk < 2; kk++)
            #pragma unroll
            for (int mi = 0; mi < 4; mi++)
                #pragma unroll
                for (int ni = 0; ni < 4; ni++)
                    acc[mi][ni] = __builtin_amdgcn_mfma_f32_16x16x32_bf16(
                        af[mi][kk], bfr[ni][kk], acc[mi][ni], 0, 0, 0);
        __syncthreads();
    }

    if (SPLIT > 1) {
        float* pf = outF + (size_t)kz * M * N;
        #pragma unroll
        for (int mi = 0; mi < 4; mi++)
            #pragma unroll
            for (int ni = 0; ni < 4; ni++) {
                const int col = n0 + wn + ni * 16 + lr;
                #pragma unroll
                for (int r = 0; r < 4; r++) {
                    const int rowg = m0 + wm + mi * 16 + lh * 4 + r;
                    pf[(size_t)rowg * N + col] = acc[mi][ni][r];
                }
            }
        return;
    }

    #pragma unroll
    for (int mi = 0; mi < 4; mi++) {
        #pragma unroll
        for (int ni = 0; ni < 4; ni++) {
            const int col = n0 + wn + ni * 16 + lr;
            const float bv = bias[col];
            #pragma unroll
            for (int r = 0; r < 4; r++) {
                const int rowg = m0 + wm + mi * 16 + lh * 4 + r;
                float v = acc[mi][ni][r] + bv;
                if (RES) v += res[(size_t)rowg * N + col];
                if (GELU) v = v * (1.0f / (1.0f + __expf(-1.702f * v)));
                if (OUTF) outF[(size_t)rowg * N + col] = v;
                if (OUTB) outB[(size_t)rowg * N + col] = f2bf(v);
            }
        }
    }
}

// ---------------------------------------------------------------------------
// Split-K reduce: out = sum(parts[0..3]) + bias + res   (f32, vectorized x4)
// ---------------------------------------------------------------------------
__global__ __launch_bounds__(256) void reduce4_kernel(
    const float* __restrict__ parts, const float* __restrict__ bias,
    const float* __restrict__ res, float* __restrict__ out, int N, size_t MN)
{
    const size_t i4 = ((size_t)blockIdx.x * 256 + threadIdx.x) * 4;
    if (i4 >= MN) return;
    float4v a = *reinterpret_cast<const float4v*>(parts + i4);
    a += *reinterpret_cast<const float4v*>(parts + MN + i4);
    a += *reinterpret_cast<const float4v*>(parts + 2 * MN + i4);
    a += *reinterpret_cast<const float4v*>(parts + 3 * MN + i4);
    a += *reinterpret_cast<const float4v*>(res + i4);
    const int col = (int)(i4 % N);
    a += *reinterpret_cast<const float4v*>(bias + col);
    *reinterpret_cast<float4v*>(out + i4) = a;
}

// ---------------------------------------------------------------------------
// RoPE + repack: qkv bf16 [S][3840] -> q,k bf16 [H][S][96] (pad 80->96),
// v -> VT bf16 [H][80][S].  q is pre-scaled by 1/sqrt(80).
// ---------------------------------------------------------------------------
__global__ __launch_bounds__(256) void rope_kernel(
    const u16* __restrict__ qkv, const float* __restrict__ freqs,
    u16* __restrict__ qp, u16* __restrict__ kp, u16* __restrict__ vt)
{
    const int s = blockIdx.x, t = threadIdx.x;
    const float scale = 0.1118033988749895f;  // 1/sqrt(80)
    __shared__ float cs[40], sn[40];
    if (t < 40) {
        const float f = freqs[(size_t)s * 40 + t];
        cs[t] = cosf(f);
        sn[t] = sinf(f);
    }
    __syncthreads();
    const u16* row = qkv + (size_t)s * 3840;
    for (int i = t; i < 1280; i += 256) {
        const int h = i / 80, d = i % 80;
        const float c = cs[d >> 1], sv = sn[d >> 1];
        const float q0 = bf2f(row[i]);
        const float q1 = (d < 40) ? -bf2f(row[i + 40]) : bf2f(row[i - 40]);
        qp[((size_t)h * 3072 + s) * 96 + d] = f2bf((q0 * c + q1 * sv) * scale);
        const float k0 = bf2f(row[1280 + i]);
        const float k1 = (d < 40) ? -bf2f(row[1280 + i + 40]) : bf2f(row[1280 + i - 40]);
        kp[((size_t)h * 3072 + s) * 96 + d] = f2bf(k0 * c + k1 * sv);
        vt[((size_t)h * 80 + d) * 3072 + s] = row[2560 + i];
    }
    {
        const int h = t / 16, d = 80 + (t % 16);
        qp[((size_t)h * 3072 + s) * 96 + d] = 0;
        kp[((size_t)h * 3072 + s) * 96 + d] = 0;
    }
}

// ---------------------------------------------------------------------------
// Flash attention v4: swapped-operand QK^T (S^T layout -> q-row lane-local),
// K and V both read from global per-lane (L1-broadcast across 4 waves, L2
// per-XCD via panel swizzle). NO LDS K, NO barriers in the loop. P via tiny
// per-wave LDS tile. Defer-max (THR=8). Online softmax with scalar m,l.
// ---------------------------------------------------------------------------
__global__ __launch_bounds__(256) void attn_kernel(
    const u16* __restrict__ qp, const u16* __restrict__ kp,
    const u16* __restrict__ vt, u16* __restrict__ attn_out)
{
    const int tid = threadIdx.x, lane = tid & 63, wave = tid >> 6;
    const int w = xcd_swz(blockIdx.x, 768);
    const int qt = w & 15;          // q-tile within segment
    const int h = (w >> 4) & 15;    // head
    const int seg = w >> 8;         // segment
    const int lr = lane & 15, lh = lane >> 4;
    const int qrow = seg * 1024 + qt * 64 + wave * 16;

    __shared__ u16 P[4][16 * 72];   // per-wave P tile [q][kv], 144B rows

    // Q fragments (B-operand): col=lane&15 -> q-row = lr, k = d0*32+lh*8+j
    bf16x8 aq[3];
    {
        const u16* qb = qp + ((size_t)h * 3072 + qrow + lr) * 96 + lh * 8;
        #pragma unroll
        for (int d0 = 0; d0 < 3; d0++)
            aq[d0] = *reinterpret_cast<const bf16x8*>(qb + d0 * 32);
    }

    // per-lane scalars: this lane's q-row is lr
    float m = -1e30f, l = 0.f;
    f32x4 acc[5] = {};   // O^T: d = df*16+lh*4+r, q = lr

    const u16* kseg = kp + ((size_t)h * 3072 + seg * 1024) * 96;
    // K A-frag base: row = kv = c*16+lr, k-elem = d0*32+lh*8
    const u16* kfb = kseg + (size_t)lr * 96 + lh * 8;
    // V A-frag base: row = d = df*16+lr, k-elem(kv) = lh*8
    const u16* vbase = vt + ((size_t)h * 80 + lr) * 3072 + seg * 1024 + lh * 8;

    for (int t = 0; t < 16; t++) {
        // --- K fragments from global (L1/L2 resident) ---
        bf16x8 kf[4][3];
        const u16* kt = kfb + (size_t)t * 64 * 96;
        #pragma unroll
        for (int c = 0; c < 4; c++)
            #pragma unroll
            for (int d0 = 0; d0 < 3; d0++)
                kf[c][d0] = *reinterpret_cast<const bf16x8*>(kt + c * 16 * 96 + d0 * 32);

        // --- QK^T swapped: S^T[kv][q] ; sc[c][r]: kv=c*16+lh*4+r, q=lr ---
        f32x4 sc[4] = {};
        #pragma unroll
        for (int c = 0; c < 4; c++)
            #pragma unroll
            for (int d0 = 0; d0 < 3; d0++)
                sc[c] = __builtin_amdgcn_mfma_f32_16x16x32_bf16(kf[c][d0], aq[d0], sc[c], 0, 0, 0);

        // --- V fragments (independent; issued during softmax) ---
        bf16x8 vf[2][5];
        #pragma unroll
        for (int ks = 0; ks < 2; ks++)
            #pragma unroll
            for (int df = 0; df < 5; df++)
                vf[ks][df] = *reinterpret_cast<const bf16x8*>(
                    vbase + (size_t)df * 16 * 3072 + t * 64 + ks * 32);

        // --- online softmax, q-row local (16 vals/lane, x4 lanes via lh) ---
        float pmax = sc[0][0];
        #pragma unroll
        for (int c = 0; c < 4; c++)
            #pragma unroll
            for (int r = 0; r < 4; r++)
                pmax = fmaxf(pmax, sc[c][r]);
        pmax = fmaxf(pmax, __shfl_xor(pmax, 16));
        pmax = fmaxf(pmax, __shfl_xor(pmax, 32));

        if (!__all(pmax - m <= 8.0f)) {          // defer-max (T13)
            const float mn = fmaxf(m, pmax);
            const float fac = __expf(m - mn);
            m = mn;
            l *= fac;
            #pragma unroll
            for (int df = 0; df < 5; df++)
                #pragma unroll
                for (int r = 0; r < 4; r++)
                    acc[df][r] *= fac;
        }

        float p[4][4], rs = 0.f;
        #pragma unroll
        for (int c = 0; c < 4; c++)
            #pragma unroll
            for (int r = 0; r < 4; r++) {
                p[c][r] = __expf(sc[c][r] - m);
                rs += p[c][r];
            }
        rs += __shfl_xor(rs, 16);
        rs += __shfl_xor(rs, 32);
        l += rs;

        // --- P -> LDS [q=lr][kv], 4x ds_write_b64 ---
        #pragma unroll
        for (int c = 0; c < 4; c++) {
            u16x4 pw;
            #pragma unroll
            for (int r = 0; r < 4; r++)
                pw[r] = f2bf(p[c][r]);
            *reinterpret_cast<u16x4*>((char*)P[wave] + lr * 144 + c * 32 + lh * 8) = pw;
        }
        asm volatile("s_waitcnt lgkmcnt(0)" ::: "memory");

        // --- PV swapped: O^T = V^T @ P ; A=V^T, B=P ---
        #pragma unroll
        for (int ks = 0; ks < 2; ks++) {
            bf16x8 pa = *reinterpret_cast<const bf16x8*>(
                (const char*)P[wave] + lr * 144 + ks * 64 + lh * 16);
            #pragma unroll
            for (int df = 0; df < 5; df++)
                acc[df] = __builtin_amdgcn_mfma_f32_16x16x32_bf16(vf[ks][df], pa, acc[df], 0, 0, 0);
        }
    }

    // epilogue: O^T -> attn_out[q][h*80+d]; lane owns q=lr, d=df*16+lh*4+r
    const float invl = 1.0f / l;
    u16* orow = attn_out + (size_t)(qrow + lr) * 1280 + h * 80;
    #pragma unroll
    for (int df = 0; df < 5; df++) {
        u16x4 o;
        #pragma unroll
        for (int r = 0; r < 4; r++)
            o[r] = f2bf(acc[df][r] * invl);
        *reinterpret_cast<u16x4*>(orow + df * 16 + lh * 4) = o;
    }
}

// ---------------------------------------------------------------------------
extern "C" void kernel_launch(void* const* d_in, const int* in_sizes, int n_in,
                              void* d_out, int out_size, void* d_ws, size_t ws_size,
                              hipStream_t stream) {
    const float* hidden = (const float*)d_in[0];
    const float* rot    = (const float*)d_in[1];
    const float* ln1s   = (const float*)d_in[2];
    const float* ln1b   = (const float*)d_in[3];
    const float* ln2s   = (const float*)d_in[4];
    const float* ln2b   = (const float*)d_in[5];
    const float* qkvw   = (const float*)d_in[6];
    const float* qkvb   = (const float*)d_in[7];
    const float* projw  = (const float*)d_in[8];
    const float* projb  = (const float*)d_in[9];
    const float* fc1w   = (const float*)d_in[10];
    const float* fc1b   = (const float*)d_in[11];
    const float* fc2w   = (const float*)d_in[12];
    const float* fc2b   = (const float*)d_in[13];
    // cu_seqlens fixed [0,1024,2048,3072] -> 3 segments of 1024.
    float* out = (float*)d_out;

    char* p = (char*)d_ws;
    auto alloc = [&](size_t n) { char* r = p; p += (n + 255) & ~(size_t)255; return r; };
    u16* qkvwT  = (u16*)alloc((size_t)3840 * 1280 * 2);
    u16* projwT = (u16*)alloc((size_t)1280 * 1280 * 2);
    u16* fc1wT  = (u16*)alloc((size_t)5120 * 1280 * 2);
    u16* fc2wT  = (u16*)alloc((size_t)1280 * 5120 * 2);
    u16* hbuf   = (u16*)alloc((size_t)3072 * 1280 * 2);        // reused as h2
    u16* qkvbf  = (u16*)alloc((size_t)3072 * 5120 * 2);        // qkv bf16; reused as mlp1
    u16* attnb  = (u16*)alloc((size_t)3072 * 1280 * 2);
    float* xmid = (float*)alloc((size_t)3072 * 1280 * 4);
    // union region: {qp,kp,vt} (26.7 MB, dead after attn)  /  split-K parts (62.9 MB)
    float* parts = (float*)alloc((size_t)4 * 3072 * 1280 * 4);
    u16* qp2 = (u16*)parts;
    u16* kp2 = qp2 + (size_t)16 * 3072 * 96;
    u16* vt2 = kp2 + (size_t)16 * 3072 * 96;
    u16* h2   = hbuf;
    u16* mlp1 = qkvbf;
    const size_t MN = (size_t)3072 * 1280;

    transpose_kernel<<<dim3(3840 / 64, 1280 / 64), 256, 0, stream>>>(qkvw, qkvwT, 1280, 3840);
    transpose_kernel<<<dim3(1280 / 64, 1280 / 64), 256, 0, stream>>>(projw, projwT, 1280, 1280);
    transpose_kernel<<<dim3(5120 / 64, 1280 / 64), 256, 0, stream>>>(fc1w, fc1wT, 1280, 5120);
    transpose_kernel<<<dim3(1280 / 64, 5120 / 64), 256, 0, stream>>>(fc2w, fc2wT, 5120, 1280);

    ln_kernel<<<3072, 256, 0, stream>>>(hidden, ln1s, ln1b, hbuf);
    gemm_kernel<0, 0, 0, 1, 1><<<dim3(30, 24), 256, 0, stream>>>(
        hbuf, qkvwT, qkvb, nullptr, nullptr, qkvbf, 3072, 3840, 1280);
    rope_kernel<<<3072, 256, 0, stream>>>(qkvbf, rot, qp2, kp2, vt2);
    attn_kernel<<<768, 256, 0, stream>>>(qp2, kp2, vt2, attnb);
    gemm_kernel<0, 0, 1, 0, 4><<<dim3(10, 24, 4), 256, 0, stream>>>(
        attnb, projwT, projb, nullptr, parts, nullptr, 3072, 1280, 1280);
    reduce4_kernel<<<(int)(MN / 4 / 256), 256, 0, stream>>>(parts, projb, hidden, xmid, 1280, MN);
    ln_kernel<<<3072, 256, 0, stream>>>(xmid, ln2s, ln2b, h2);
    gemm_kernel<1, 0, 0, 1, 1><<<dim3(40, 24), 256, 0, stream>>>(
        h2, fc1wT, fc1b, nullptr, nullptr, mlp1, 3072, 5120, 1280);
    gemm_kernel<0, 0, 1, 0, 4><<<dim3(10, 24, 4), 256, 0, stream>>>(
        mlp1, fc2wT, fc2b, nullptr, parts, nullptr, 3072, 1280, 5120);
    reduce4_kernel<<<(int)(MN / 4 / 256), 256, 0, stream>>>(parts, fc2b, xmid, out, 1280, MN);
}

// Round 6
// 361.351 us; speedup vs baseline: 1.1135x; 1.1135x over previous
//
#include <hip/hip_runtime.h>

typedef __bf16 bf16x8 __attribute__((ext_vector_type(8)));
typedef float f32x4 __attribute__((ext_vector_type(4)));
typedef unsigned short u16;
typedef u16 u16x4 __attribute__((ext_vector_type(4)));
typedef u16 u16x8 __attribute__((ext_vector_type(8)));
typedef float float4v __attribute__((ext_vector_type(4)));

__device__ __forceinline__ u16 f2bf(float f) {
    __bf16 b = (__bf16)f;
    return __builtin_bit_cast(unsigned short, b);
}
__device__ __forceinline__ float bf2f(u16 x) {
    __bf16 b = __builtin_bit_cast(__bf16, x);
    return (float)b;
}

__device__ __forceinline__ void gld16(const void* g, void* l) {
    __builtin_amdgcn_global_load_lds((const __attribute__((address_space(1))) void*)g,
                                     (__attribute__((address_space(3))) void*)l, 16, 0, 0);
}

// bijective XCD chunk swizzle (m204)
__device__ __forceinline__ int xcd_swz(int orig, int nwg) {
    const int q = nwg >> 3, r = nwg & 7;
    const int xcd = orig & 7, pos = orig >> 3;
    return (xcd < r ? xcd * (q + 1) : r * (q + 1) + (xcd - r) * q) + pos;
}

// ---------------------------------------------------------------------------
// Weight transpose + f32->bf16 cast:  W[K][N] f32  ->  WT[N][K] bf16
// ---------------------------------------------------------------------------
__global__ __launch_bounds__(256) void transpose_kernel(
    const float* __restrict__ W, u16* __restrict__ WT, int K, int N)
{
    __shared__ u16 tile[64][65];
    const int tx = threadIdx.x & 63, ty = threadIdx.x >> 6;
    const int n0 = blockIdx.x * 64, k0 = blockIdx.y * 64;
    #pragma unroll
    for (int i = ty; i < 64; i += 4)
        tile[i][tx] = f2bf(W[(size_t)(k0 + i) * N + n0 + tx]);
    __syncthreads();
    #pragma unroll
    for (int i = ty; i < 64; i += 4)
        WT[(size_t)(n0 + i) * K + k0 + tx] = tile[tx][i];
}

// ---------------------------------------------------------------------------
// LayerNorm: x f32 [3072][1280] -> out bf16
// ---------------------------------------------------------------------------
__global__ __launch_bounds__(256) void ln_kernel(
    const float* __restrict__ x, const float* __restrict__ sc,
    const float* __restrict__ bias, u16* __restrict__ out)
{
    const int row = blockIdx.x, t = threadIdx.x;
    const float* xr = x + (size_t)row * 1280;
    float v[5], s1 = 0.f, s2 = 0.f;
    #pragma unroll
    for (int i = 0; i < 5; i++) {
        v[i] = xr[t + i * 256];
        s1 += v[i];
        s2 += v[i] * v[i];
    }
    #pragma unroll
    for (int off = 32; off; off >>= 1) {
        s1 += __shfl_down(s1, off);
        s2 += __shfl_down(s2, off);
    }
    __shared__ float rA[4], rB[4];
    if ((t & 63) == 0) { rA[t >> 6] = s1; rB[t >> 6] = s2; }
    __syncthreads();
    s1 = rA[0] + rA[1] + rA[2] + rA[3];
    s2 = rB[0] + rB[1] + rB[2] + rB[3];
    const float mu = s1 * (1.f / 1280.f);
    const float var = s2 * (1.f / 1280.f) - mu * mu;
    const float rstd = rsqrtf(var + 1e-6f);
    #pragma unroll
    for (int i = 0; i < 5; i++) {
        const int d = t + i * 256;
        out[(size_t)row * 1280 + d] = f2bf((v[i] - mu) * rstd * sc[d] + bias[d]);
    }
}

// ---------------------------------------------------------------------------
// Generic bf16 MFMA GEMM: C = A[M][K] @ BT[N][K]^T (+bias/res/gelu when SPLIT==1)
// 128x128 tile, BK=64, 4 waves, global_load_lds + XOR swizzle, XCD swizzle.
// SPLIT>1: blockIdx.z = K-slice; raw partial f32 -> outF + z*M*N (no bias).
// ---------------------------------------------------------------------------
template <int GELU, int RES, int OUTF, int OUTB, int SPLIT>
__global__ __launch_bounds__(256) void gemm_kernel(
    const u16* __restrict__ A, const u16* __restrict__ BT,
    const float* __restrict__ bias, const float* __restrict__ res,
    float* __restrict__ outF, u16* __restrict__ outB,
    int M, int N, int K)
{
    __shared__ u16 As[128 * 64];   // [row][64 bf16], 128B rows
    __shared__ u16 Bs[128 * 64];
    const int tid = threadIdx.x, lane = tid & 63, wave = tid >> 6;
    const int nwg = gridDim.x * gridDim.y;
    const int bid = xcd_swz(blockIdx.y * gridDim.x + blockIdx.x, nwg);
    const int m0 = (bid / gridDim.x) * 128, n0 = (bid % gridDim.x) * 128;
    const int wm = (wave >> 1) * 64, wn = (wave & 1) * 64;
    const int lr = lane & 15, lh = lane >> 4;
    const int srow = lane >> 3;
    const int schunk = (lane & 7) ^ (srow & 7);

    const int kchunk = K / SPLIT;
    const int kz = (SPLIT > 1) ? blockIdx.z : 0;
    const int kbeg = kz * kchunk, kend = kbeg + kchunk;

    f32x4 acc[4][4] = {};

    for (int k0 = kbeg; k0 < kend; k0 += 64) {
        #pragma unroll
        for (int s = 0; s < 4; s++) {
            const int seg = wave + s * 4;          // 0..15
            const int row = seg * 8 + srow;        // 0..127
            gld16(A + (size_t)(m0 + row) * K + k0 + schunk * 8, &As[seg * 512]);
            gld16(BT + (size_t)(n0 + row) * K + k0 + schunk * 8, &Bs[seg * 512]);
        }
        asm volatile("s_waitcnt vmcnt(0)" ::: "memory");
        __syncthreads();

        bf16x8 af[4][2], bfr[4][2];
        #pragma unroll
        for (int mi = 0; mi < 4; mi++) {
            const int row = wm + mi * 16 + lr;
            #pragma unroll
            for (int kk = 0; kk < 2; kk++) {
                const int cb = (kk * 64 + lh * 16) ^ ((row & 7) << 4);
                af[mi][kk] = *reinterpret_cast<const bf16x8*>((const char*)As + row * 128 + cb);
            }
        }
        #pragma unroll
        for (int ni = 0; ni < 4; ni++) {
            const int row = wn + ni * 16 + lr;
            #pragma unroll
            for (int kk = 0; kk < 2; kk++) {
                const int cb = (kk * 64 + lh * 16) ^ ((row & 7) << 4);
                bfr[ni][kk] = *reinterpret_cast<const bf16x8*>((const char*)Bs + row * 128 + cb);
            }
        }
        #pragma unroll
        for (int kk = 0; kk < 2; kk++)
            #pragma unroll
            for (int mi = 0; mi < 4; mi++)
                #pragma unroll
                for (int ni = 0; ni < 4; ni++)
                    acc[mi][ni] = __builtin_amdgcn_mfma_f32_16x16x32_bf16(
                        af[mi][kk], bfr[ni][kk], acc[mi][ni], 0, 0, 0);
        __syncthreads();
    }

    if (SPLIT > 1) {
        float* pf = outF + (size_t)kz * M * N;
        #pragma unroll
        for (int mi = 0; mi < 4; mi++)
            #pragma unroll
            for (int ni = 0; ni < 4; ni++) {
                const int col = n0 + wn + ni * 16 + lr;
                #pragma unroll
                for (int r = 0; r < 4; r++) {
                    const int rowg = m0 + wm + mi * 16 + lh * 4 + r;
                    pf[(size_t)rowg * N + col] = acc[mi][ni][r];
                }
            }
        return;
    }

    #pragma unroll
    for (int mi = 0; mi < 4; mi++) {
        #pragma unroll
        for (int ni = 0; ni < 4; ni++) {
            const int col = n0 + wn + ni * 16 + lr;
            const float bv = bias[col];
            #pragma unroll
            for (int r = 0; r < 4; r++) {
                const int rowg = m0 + wm + mi * 16 + lh * 4 + r;
                float v = acc[mi][ni][r] + bv;
                if (RES) v += res[(size_t)rowg * N + col];
                if (GELU) v = v * (1.0f / (1.0f + __expf(-1.702f * v)));
                if (OUTF) outF[(size_t)rowg * N + col] = v;
                if (OUTB) outB[(size_t)rowg * N + col] = f2bf(v);
            }
        }
    }
}

// ---------------------------------------------------------------------------
// Split-K reduce: out = sum(parts[0..3]) + bias + res   (f32, vectorized x4)
// ---------------------------------------------------------------------------
__global__ __launch_bounds__(256) void reduce4_kernel(
    const float* __restrict__ parts, const float* __restrict__ bias,
    const float* __restrict__ res, float* __restrict__ out, int N, size_t MN)
{
    const size_t i4 = ((size_t)blockIdx.x * 256 + threadIdx.x) * 4;
    if (i4 >= MN) return;
    float4v a = *reinterpret_cast<const float4v*>(parts + i4);
    a += *reinterpret_cast<const float4v*>(parts + MN + i4);
    a += *reinterpret_cast<const float4v*>(parts + 2 * MN + i4);
    a += *reinterpret_cast<const float4v*>(parts + 3 * MN + i4);
    a += *reinterpret_cast<const float4v*>(res + i4);
    const int col = (int)(i4 % N);
    a += *reinterpret_cast<const float4v*>(bias + col);
    *reinterpret_cast<float4v*>(out + i4) = a;
}

// ---------------------------------------------------------------------------
// RoPE + repack: qkv bf16 [S][3840] -> q bf16 [H][S][96] (pre-scaled 1/sqrt(80)),
// k bf16 [H][S][128] (pad 80->128 with zeros, XOR-closed chunk space),
// v -> VT bf16 [H][80][S]
// ---------------------------------------------------------------------------
__global__ __launch_bounds__(256) void rope_kernel(
    const u16* __restrict__ qkv, const float* __restrict__ freqs,
    u16* __restrict__ qp, u16* __restrict__ kp, u16* __restrict__ vt)
{
    const int s = blockIdx.x, t = threadIdx.x;
    const float scale = 0.1118033988749895f;  // 1/sqrt(80)
    __shared__ float cs[40], sn[40];
    if (t < 40) {
        const float f = freqs[(size_t)s * 40 + t];
        cs[t] = cosf(f);
        sn[t] = sinf(f);
    }
    __syncthreads();
    const u16* row = qkv + (size_t)s * 3840;
    for (int i = t; i < 1280; i += 256) {
        const int h = i / 80, d = i % 80;
        const float c = cs[d >> 1], sv = sn[d >> 1];
        const float q0 = bf2f(row[i]);
        const float q1 = (d < 40) ? -bf2f(row[i + 40]) : bf2f(row[i - 40]);
        qp[((size_t)h * 3072 + s) * 96 + d] = f2bf((q0 * c + q1 * sv) * scale);
        const float k0 = bf2f(row[1280 + i]);
        const float k1 = (d < 40) ? -bf2f(row[1280 + i + 40]) : bf2f(row[1280 + i - 40]);
        kp[((size_t)h * 3072 + s) * 128 + d] = f2bf(k0 * c + k1 * sv);
        vt[((size_t)h * 80 + d) * 3072 + s] = row[2560 + i];
    }
    // pad q cols 80..95
    {
        const int h = t / 16, d = 80 + (t % 16);
        qp[((size_t)h * 3072 + s) * 96 + d] = 0;
    }
    // pad k cols 80..127 (16 heads x 48)
    for (int i = t; i < 768; i += 256) {
        const int h = i / 48, d = 80 + (i % 48);
        kp[((size_t)h * 3072 + s) * 128 + d] = 0;
    }
}

// ---------------------------------------------------------------------------
// Flash attention v5: swapped QK^T (q-row lane-local softmax, scalar m/l),
// K AND V staged via global_load_lds (linear dest = zero write conflicts;
// source pre-swizzled chunk^=row&7; reads XOR-swizzled -> 2-way max).
// Double-buffered; staging issued at iter top, lands under QK+softmax.
// No scattered global vector loads anywhere in the loop.
// ---------------------------------------------------------------------------
__global__ __launch_bounds__(256) void attn_kernel(
    const u16* __restrict__ qp, const u16* __restrict__ kp,
    const u16* __restrict__ vt, u16* __restrict__ attn_out)
{
    const int tid = threadIdx.x, lane = tid & 63, wave = tid >> 6;
    const int w = xcd_swz(blockIdx.x, 768);
    const int qt = w & 15;          // q-tile within segment
    const int h = (w >> 4) & 15;    // head
    const int sq = w >> 8;          // sequence segment
    const int lr = lane & 15, lh = lane >> 4;
    const int qrow = sq * 1024 + qt * 64 + wave * 16;

    __shared__ u16 Ks[2][64 * 128];   // [kv 64][128 u16 padded], 256B rows
    __shared__ u16 Vs[2][80 * 64];    // [d 80][64 u16], 128B rows
    __shared__ u16 P[4][16 * 72];     // per-wave P [q 16][kv 64+pad]

    // ---- Q fragments (B-operand): q-row = lr, k = d0*32+lh*8+j ----
    bf16x8 aq[3];
    {
        const u16* qb = qp + ((size_t)h * 3072 + qrow + lr) * 96 + lh * 8;
        #pragma unroll
        for (int d0 = 0; d0 < 3; d0++)
            aq[d0] = *reinterpret_cast<const bf16x8*>(qb + d0 * 32);
    }

    float m = -1e30f, l = 0.f;
    f32x4 acc[5] = {};   // O^T: d = df*16+lh*4+r, q = lr

    const u16* kseg = kp + ((size_t)h * 3072 + sq * 1024) * 128;
    const u16* vseg = vt + (size_t)h * 80 * 3072 + sq * 1024;

    // staging lane coords
    const int krow_l = lane >> 4;             // row within 4-row K segment
    const int kch    = lane & 15;             // 16B chunk
    const int vrow_l = lane >> 3;             // row within 8-row V segment
    const int vch    = lane & 7;

    // stage K tile t into Ks[buf], V tile t into Vs[buf]
    auto stageK = [&](int t, int buf) {
        #pragma unroll
        for (int s = 0; s < 4; s++) {
            const int seg = wave + s * 4;             // 0..15
            const int row = seg * 4 + krow_l;         // 0..63
            gld16(kseg + (size_t)(t * 64 + row) * 128 + ((kch ^ (row & 7)) * 8),
                  &Ks[buf][seg * 512]);
        }
    };
    auto stageV = [&](int t, int buf) {
        #pragma unroll
        for (int s = 0; s < 3; s++) {
            const int seg = wave + s * 4;             // 0..11, use <10
            if (seg < 10) {
                const int row = seg * 8 + vrow_l;     // 0..79
                gld16(vseg + (size_t)row * 3072 + t * 64 + ((vch ^ (row & 7)) * 8),
                      &Vs[buf][seg * 512]);
            }
        }
    };

    stageK(0, 0);
    stageV(0, 0);
    asm volatile("s_waitcnt vmcnt(0)" ::: "memory");
    __syncthreads();

    for (int t = 0; t < 16; t++) {
        const int cur = t & 1;
        if (t < 15) {                 // issue next-tile staging early
            stageK(t + 1, cur ^ 1);
            stageV(t + 1, cur ^ 1);
        }

        // --- QK^T swapped: sc[c][r]: kv = c*16+lh*4+r, q = lr ---
        f32x4 sc[4] = {};
        #pragma unroll
        for (int c = 0; c < 4; c++) {
            #pragma unroll
            for (int d0 = 0; d0 < 3; d0++) {
                const int row = c * 16 + lr;
                const int rb = row * 256 + (((d0 * 4 + lh) ^ (row & 7)) << 4);
                bf16x8 kf = *reinterpret_cast<const bf16x8*>((const char*)Ks[cur] + rb);
                sc[c] = __builtin_amdgcn_mfma_f32_16x16x32_bf16(kf, aq[d0], sc[c], 0, 0, 0);
            }
        }

        // --- online softmax (q pre-scaled), defer-max ---
        float pmax = sc[0][0];
        #pragma unroll
        for (int c = 0; c < 4; c++)
            #pragma unroll
            for (int r = 0; r < 4; r++)
                pmax = fmaxf(pmax, sc[c][r]);
        pmax = fmaxf(pmax, __shfl_xor(pmax, 16));
        pmax = fmaxf(pmax, __shfl_xor(pmax, 32));

        if (!__all(pmax - m <= 8.0f)) {
            const float mn = fmaxf(m, pmax);
            const float fac = __expf(m - mn);
            m = mn;
            l *= fac;
            #pragma unroll
            for (int df = 0; df < 5; df++)
                #pragma unroll
                for (int r = 0; r < 4; r++)
                    acc[df][r] *= fac;
        }

        float p[4][4], rs = 0.f;
        #pragma unroll
        for (int c = 0; c < 4; c++)
            #pragma unroll
            for (int r = 0; r < 4; r++) {
                p[c][r] = __expf(sc[c][r] - m);
                rs += p[c][r];
            }
        rs += __shfl_xor(rs, 16);
        rs += __shfl_xor(rs, 32);
        l += rs;

        // --- P -> LDS [q=lr][kv], 4x ds_write_b64 ---
        #pragma unroll
        for (int c = 0; c < 4; c++) {
            u16x4 pw;
            #pragma unroll
            for (int r = 0; r < 4; r++)
                pw[r] = f2bf(p[c][r]);
            *reinterpret_cast<u16x4*>((char*)P[wave] + lr * 144 + c * 32 + lh * 8) = pw;
        }
        asm volatile("s_waitcnt lgkmcnt(0)" ::: "memory");

        // --- PV swapped: O^T = V^T @ P ; A = Vs (swizzled read), B = P ---
        #pragma unroll
        for (int ks = 0; ks < 2; ks++) {
            bf16x8 pa = *reinterpret_cast<const bf16x8*>(
                (const char*)P[wave] + lr * 144 + ks * 64 + lh * 16);
            #pragma unroll
            for (int df = 0; df < 5; df++) {
                const int row = df * 16 + lr;
                const int vb = row * 128 + (((ks * 4 + lh) ^ (row & 7)) << 4);
                bf16x8 vf = *reinterpret_cast<const bf16x8*>((const char*)Vs[cur] + vb);
                acc[df] = __builtin_amdgcn_mfma_f32_16x16x32_bf16(vf, pa, acc[df], 0, 0, 0);
            }
        }

        asm volatile("s_waitcnt vmcnt(0)" ::: "memory");   // next-tile staging landed
        __syncthreads();
    }

    // epilogue: O^T -> attn_out[q][h*80+d]; lane owns q=lr, d=df*16+lh*4+r
    const float invl = 1.0f / l;
    u16* orow = attn_out + (size_t)(qrow + lr) * 1280 + h * 80;
    #pragma unroll
    for (int df = 0; df < 5; df++) {
        u16x4 o;
        #pragma unroll
        for (int r = 0; r < 4; r++)
            o[r] = f2bf(acc[df][r] * invl);
        *reinterpret_cast<u16x4*>(orow + df * 16 + lh * 4) = o;
    }
}

// ---------------------------------------------------------------------------
extern "C" void kernel_launch(void* const* d_in, const int* in_sizes, int n_in,
                              void* d_out, int out_size, void* d_ws, size_t ws_size,
                              hipStream_t stream) {
    const float* hidden = (const float*)d_in[0];
    const float* rot    = (const float*)d_in[1];
    const float* ln1s   = (const float*)d_in[2];
    const float* ln1b   = (const float*)d_in[3];
    const float* ln2s   = (const float*)d_in[4];
    const float* ln2b   = (const float*)d_in[5];
    const float* qkvw   = (const float*)d_in[6];
    const float* qkvb   = (const float*)d_in[7];
    const float* projw  = (const float*)d_in[8];
    const float* projb  = (const float*)d_in[9];
    const float* fc1w   = (const float*)d_in[10];
    const float* fc1b   = (const float*)d_in[11];
    const float* fc2w   = (const float*)d_in[12];
    const float* fc2b   = (const float*)d_in[13];
    // cu_seqlens fixed [0,1024,2048,3072] -> 3 segments of 1024.
    float* out = (float*)d_out;

    char* p = (char*)d_ws;
    auto alloc = [&](size_t n) { char* r = p; p += (n + 255) & ~(size_t)255; return r; };
    u16* qkvwT  = (u16*)alloc((size_t)3840 * 1280 * 2);
    u16* projwT = (u16*)alloc((size_t)1280 * 1280 * 2);
    u16* fc1wT  = (u16*)alloc((size_t)5120 * 1280 * 2);
    u16* fc2wT  = (u16*)alloc((size_t)1280 * 5120 * 2);
    u16* hbuf   = (u16*)alloc((size_t)3072 * 1280 * 2);        // reused as h2
    u16* qkvbf  = (u16*)alloc((size_t)3072 * 5120 * 2);        // qkv bf16; reused as mlp1
    u16* attnb  = (u16*)alloc((size_t)3072 * 1280 * 2);
    float* xmid = (float*)alloc((size_t)3072 * 1280 * 4);
    // union region: {qp,kp,vt} (~30 MB, dead after attn) / split-K parts (62.9 MB)
    float* parts = (float*)alloc((size_t)4 * 3072 * 1280 * 4);
    u16* qp2 = (u16*)parts;                                    // [16][3072][96]
    u16* kp2 = qp2 + (size_t)16 * 3072 * 96;                   // [16][3072][128]
    u16* vt2 = kp2 + (size_t)16 * 3072 * 128;                  // [16][80][3072]
    u16* h2   = hbuf;
    u16* mlp1 = qkvbf;
    const size_t MN = (size_t)3072 * 1280;

    transpose_kernel<<<dim3(3840 / 64, 1280 / 64), 256, 0, stream>>>(qkvw, qkvwT, 1280, 3840);
    transpose_kernel<<<dim3(1280 / 64, 1280 / 64), 256, 0, stream>>>(projw, projwT, 1280, 1280);
    transpose_kernel<<<dim3(5120 / 64, 1280 / 64), 256, 0, stream>>>(fc1w, fc1wT, 1280, 5120);
    transpose_kernel<<<dim3(1280 / 64, 5120 / 64), 256, 0, stream>>>(fc2w, fc2wT, 5120, 1280);

    ln_kernel<<<3072, 256, 0, stream>>>(hidden, ln1s, ln1b, hbuf);
    gemm_kernel<0, 0, 0, 1, 1><<<dim3(30, 24), 256, 0, stream>>>(
        hbuf, qkvwT, qkvb, nullptr, nullptr, qkvbf, 3072, 3840, 1280);
    rope_kernel<<<3072, 256, 0, stream>>>(qkvbf, rot, qp2, kp2, vt2);
    attn_kernel<<<768, 256, 0, stream>>>(qp2, kp2, vt2, attnb);
    gemm_kernel<0, 0, 1, 0, 4><<<dim3(10, 24, 4), 256, 0, stream>>>(
        attnb, projwT, projb, nullptr, parts, nullptr, 3072, 1280, 1280);
    reduce4_kernel<<<(int)(MN / 4 / 256), 256, 0, stream>>>(parts, projb, hidden, xmid, 1280, MN);
    ln_kernel<<<3072, 256, 0, stream>>>(xmid, ln2s, ln2b, h2);
    gemm_kernel<1, 0, 0, 1, 1><<<dim3(40, 24), 256, 0, stream>>>(
        h2, fc1wT, fc1b, nullptr, nullptr, mlp1, 3072, 5120, 1280);
    gemm_kernel<0, 0, 1, 0, 4><<<dim3(10, 24, 4), 256, 0, stream>>>(
        mlp1, fc2wT, fc2b, nullptr, parts, nullptr, 3072, 1280, 5120);
    reduce4_kernel<<<(int)(MN / 4 / 256), 256, 0, stream>>>(parts, fc2b, xmid, out, 1280, MN);
}

// Round 7
// 351.296 us; speedup vs baseline: 1.1454x; 1.0286x over previous
//
#include <hip/hip_runtime.h>

typedef __bf16 bf16x8 __attribute__((ext_vector_type(8)));
typedef float f32x4 __attribute__((ext_vector_type(4)));
typedef unsigned short u16;
typedef u16 u16x4 __attribute__((ext_vector_type(4)));
typedef u16 u16x8 __attribute__((ext_vector_type(8)));
typedef float float4v __attribute__((ext_vector_type(4)));

__device__ __forceinline__ u16 f2bf(float f) {
    __bf16 b = (__bf16)f;
    return __builtin_bit_cast(unsigned short, b);
}
__device__ __forceinline__ float bf2f(u16 x) {
    __bf16 b = __builtin_bit_cast(__bf16, x);
    return (float)b;
}

__device__ __forceinline__ void gld16(const void* g, void* l) {
    __builtin_amdgcn_global_load_lds((const __attribute__((address_space(1))) void*)g,
                                     (__attribute__((address_space(3))) void*)l, 16, 0, 0);
}

// bijective XCD chunk swizzle (m204)
__device__ __forceinline__ int xcd_swz(int orig, int nwg) {
    const int q = nwg >> 3, r = nwg & 7;
    const int xcd = orig & 7, pos = orig >> 3;
    return (xcd < r ? xcd * (q + 1) : r * (q + 1) + (xcd - r) * q) + pos;
}

// ---------------------------------------------------------------------------
// Weight transpose + f32->bf16 cast:  W[K][N] f32  ->  WT[N][K] bf16
// ---------------------------------------------------------------------------
__global__ __launch_bounds__(256) void transpose_kernel(
    const float* __restrict__ W, u16* __restrict__ WT, int K, int N)
{
    __shared__ u16 tile[64][65];
    const int tx = threadIdx.x & 63, ty = threadIdx.x >> 6;
    const int n0 = blockIdx.x * 64, k0 = blockIdx.y * 64;
    #pragma unroll
    for (int i = ty; i < 64; i += 4)
        tile[i][tx] = f2bf(W[(size_t)(k0 + i) * N + n0 + tx]);
    __syncthreads();
    #pragma unroll
    for (int i = ty; i < 64; i += 4)
        WT[(size_t)(n0 + i) * K + k0 + tx] = tile[tx][i];
}

// ---------------------------------------------------------------------------
// LayerNorm: x f32 [3072][1280] -> out bf16
// ---------------------------------------------------------------------------
__global__ __launch_bounds__(256) void ln_kernel(
    const float* __restrict__ x, const float* __restrict__ sc,
    const float* __restrict__ bias, u16* __restrict__ out)
{
    const int row = blockIdx.x, t = threadIdx.x;
    const float* xr = x + (size_t)row * 1280;
    float v[5], s1 = 0.f, s2 = 0.f;
    #pragma unroll
    for (int i = 0; i < 5; i++) {
        v[i] = xr[t + i * 256];
        s1 += v[i];
        s2 += v[i] * v[i];
    }
    #pragma unroll
    for (int off = 32; off; off >>= 1) {
        s1 += __shfl_down(s1, off);
        s2 += __shfl_down(s2, off);
    }
    __shared__ float rA[4], rB[4];
    if ((t & 63) == 0) { rA[t >> 6] = s1; rB[t >> 6] = s2; }
    __syncthreads();
    s1 = rA[0] + rA[1] + rA[2] + rA[3];
    s2 = rB[0] + rB[1] + rB[2] + rB[3];
    const float mu = s1 * (1.f / 1280.f);
    const float var = s2 * (1.f / 1280.f) - mu * mu;
    const float rstd = rsqrtf(var + 1e-6f);
    #pragma unroll
    for (int i = 0; i < 5; i++) {
        const int d = t + i * 256;
        out[(size_t)row * 1280 + d] = f2bf((v[i] - mu) * rstd * sc[d] + bias[d]);
    }
}

// ---------------------------------------------------------------------------
// 256x256-tile bf16 MFMA GEMM, BK=64, 8 waves (2Mx4N, 128x64 per wave).
// Stage-ahead pipeline: while computing tile i from buf[i&1], the 8
// global_load_lds for tile i+1 are issued into buf[(i+1)&1] spread across the
// 4 MFMA phases; ONE vmcnt(0)+barrier per iteration at the top drains loads
// issued a full K-tile earlier. XOR chunk swizzle (proven conflict-free).
// SPLIT>1: blockIdx.z = K-slice, raw f32 partial to outF + z*M*N.
// ---------------------------------------------------------------------------
template <int GELU, int OUTB, int SPLIT>
__global__ __launch_bounds__(512, 2) void gemm256_kernel(
    const u16* __restrict__ A, const u16* __restrict__ BT,
    const float* __restrict__ bias,
    float* __restrict__ outF, u16* __restrict__ outB,
    int M, int N, int K)
{
    __shared__ u16 As[2][256 * 64];   // [row][64 bf16], 128B rows
    __shared__ u16 Bs[2][256 * 64];
    const int tid = threadIdx.x, lane = tid & 63, wave = tid >> 6;
    const int nwg = gridDim.x * gridDim.y;
    const int bid = xcd_swz(blockIdx.y * gridDim.x + blockIdx.x, nwg);
    const int m0 = (bid / gridDim.x) * 256, n0 = (bid % gridDim.x) * 256;
    const int wr = wave >> 2, wc = wave & 3;
    const int wm = wr * 128, wn = wc * 64;
    const int lr = lane & 15, lh = lane >> 4;
    // staging: instr j covers rows j*64 + wave*8 + (lane>>3), chunk = lane&7
    const int srow_in_w = lane >> 3;      // 0..7
    const int sch = lane & 7;

    const int kchunk = K / SPLIT;
    const int kz = (SPLIT > 1) ? blockIdx.z : 0;
    const int kbeg = kz * kchunk;
    const int ntiles = kchunk >> 6;

    f32x4 acc[8][4] = {};

    // stage one A-instr and one B-instr (j in 0..3) for K-tile `tile`
    auto stageAB = [&](int tile, int buf, int j) {
        const int row = j * 64 + wave * 8 + srow_in_w;
        const size_t kq = (size_t)kbeg + tile * 64 + ((sch ^ (row & 7)) * 8);
        gld16(A + (size_t)(m0 + row) * K + kq, &As[buf][j * 4096 + wave * 512]);
        gld16(BT + (size_t)(n0 + row) * K + kq, &Bs[buf][j * 4096 + wave * 512]);
    };

    // prologue: stage tile 0 into buf 0
    #pragma unroll
    for (int j = 0; j < 4; j++) stageAB(0, 0, j);

    for (int i = 0; i < ntiles; i++) {
        const int cur = i & 1;
        asm volatile("s_waitcnt vmcnt(0)" ::: "memory");
        __syncthreads();

        // B fragments for the whole K-tile (kept live across phases)
        bf16x8 bfr[4][2];
        #pragma unroll
        for (int ni = 0; ni < 4; ni++) {
            const int row = wn + ni * 16 + lr;
            #pragma unroll
            for (int kk = 0; kk < 2; kk++) {
                const int cb = (kk * 64 + lh * 16) ^ ((row & 7) << 4);
                bfr[ni][kk] = *reinterpret_cast<const bf16x8*>((const char*)Bs[cur] + row * 128 + cb);
            }
        }

        const bool pre = (i + 1 < ntiles);
        #pragma unroll
        for (int p = 0; p < 4; p++) {
            if (pre) stageAB(i + 1, cur ^ 1, p);   // next-tile staging, issued early
            bf16x8 af[2][2];
            #pragma unroll
            for (int m2 = 0; m2 < 2; m2++) {
                const int row = wm + (p * 2 + m2) * 16 + lr;
                #pragma unroll
                for (int kk = 0; kk < 2; kk++) {
                    const int cb = (kk * 64 + lh * 16) ^ ((row & 7) << 4);
                    af[m2][kk] = *reinterpret_cast<const bf16x8*>((const char*)As[cur] + row * 128 + cb);
                }
            }
            __builtin_amdgcn_s_setprio(1);
            #pragma unroll
            for (int kk = 0; kk < 2; kk++)
                #pragma unroll
                for (int m2 = 0; m2 < 2; m2++)
                    #pragma unroll
                    for (int ni = 0; ni < 4; ni++)
                        acc[p * 2 + m2][ni] = __builtin_amdgcn_mfma_f32_16x16x32_bf16(
                            af[m2][kk], bfr[ni][kk], acc[p * 2 + m2][ni], 0, 0, 0);
            __builtin_amdgcn_s_setprio(0);
        }
    }

    if (SPLIT > 1) {
        float* pf = outF + (size_t)kz * M * N;
        #pragma unroll
        for (int mi = 0; mi < 8; mi++)
            #pragma unroll
            for (int ni = 0; ni < 4; ni++) {
                const int col = n0 + wn + ni * 16 + lr;
                #pragma unroll
                for (int r = 0; r < 4; r++) {
                    const int rowg = m0 + wm + mi * 16 + lh * 4 + r;
                    pf[(size_t)rowg * N + col] = acc[mi][ni][r];
                }
            }
        return;
    }

    #pragma unroll
    for (int mi = 0; mi < 8; mi++) {
        #pragma unroll
        for (int ni = 0; ni < 4; ni++) {
            const int col = n0 + wn + ni * 16 + lr;
            const float bv = bias[col];
            #pragma unroll
            for (int r = 0; r < 4; r++) {
                const int rowg = m0 + wm + mi * 16 + lh * 4 + r;
                float v = acc[mi][ni][r] + bv;
                if (GELU) v = v * (1.0f / (1.0f + __expf(-1.702f * v)));
                if (OUTB) outB[(size_t)rowg * N + col] = f2bf(v);
            }
        }
    }
}

// ---------------------------------------------------------------------------
// Generic 128x128 bf16 MFMA GEMM (kept for proj split-K).
// ---------------------------------------------------------------------------
template <int GELU, int RES, int OUTF, int OUTB, int SPLIT>
__global__ __launch_bounds__(256) void gemm_kernel(
    const u16* __restrict__ A, const u16* __restrict__ BT,
    const float* __restrict__ bias, const float* __restrict__ res,
    float* __restrict__ outF, u16* __restrict__ outB,
    int M, int N, int K)
{
    __shared__ u16 As[128 * 64];
    __shared__ u16 Bs[128 * 64];
    const int tid = threadIdx.x, lane = tid & 63, wave = tid >> 6;
    const int nwg = gridDim.x * gridDim.y;
    const int bid = xcd_swz(blockIdx.y * gridDim.x + blockIdx.x, nwg);
    const int m0 = (bid / gridDim.x) * 128, n0 = (bid % gridDim.x) * 128;
    const int wm = (wave >> 1) * 64, wn = (wave & 1) * 64;
    const int lr = lane & 15, lh = lane >> 4;
    const int srow = lane >> 3;
    const int schunk = (lane & 7) ^ (srow & 7);

    const int kchunk = K / SPLIT;
    const int kz = (SPLIT > 1) ? blockIdx.z : 0;
    const int kbeg = kz * kchunk, kend = kbeg + kchunk;

    f32x4 acc[4][4] = {};

    for (int k0 = kbeg; k0 < kend; k0 += 64) {
        #pragma unroll
        for (int s = 0; s < 4; s++) {
            const int seg = wave + s * 4;
            const int row = seg * 8 + srow;
            gld16(A + (size_t)(m0 + row) * K + k0 + schunk * 8, &As[seg * 512]);
            gld16(BT + (size_t)(n0 + row) * K + k0 + schunk * 8, &Bs[seg * 512]);
        }
        asm volatile("s_waitcnt vmcnt(0)" ::: "memory");
        __syncthreads();

        bf16x8 af[4][2], bfr[4][2];
        #pragma unroll
        for (int mi = 0; mi < 4; mi++) {
            const int row = wm + mi * 16 + lr;
            #pragma unroll
            for (int kk = 0; kk < 2; kk++) {
                const int cb = (kk * 64 + lh * 16) ^ ((row & 7) << 4);
                af[mi][kk] = *reinterpret_cast<const bf16x8*>((const char*)As + row * 128 + cb);
            }
        }
        #pragma unroll
        for (int ni = 0; ni < 4; ni++) {
            const int row = wn + ni * 16 + lr;
            #pragma unroll
            for (int kk = 0; kk < 2; kk++) {
                const int cb = (kk * 64 + lh * 16) ^ ((row & 7) << 4);
                bfr[ni][kk] = *reinterpret_cast<const bf16x8*>((const char*)Bs + row * 128 + cb);
            }
        }
        #pragma unroll
        for (int kk = 0; kk < 2; kk++)
            #pragma unroll
            for (int mi = 0; mi < 4; mi++)
                #pragma unroll
                for (int ni = 0; ni < 4; ni++)
                    acc[mi][ni] = __builtin_amdgcn_mfma_f32_16x16x32_bf16(
                        af[mi][kk], bfr[ni][kk], acc[mi][ni], 0, 0, 0);
        __syncthreads();
    }

    if (SPLIT > 1) {
        float* pf = outF + (size_t)kz * M * N;
        #pragma unroll
        for (int mi = 0; mi < 4; mi++)
            #pragma unroll
            for (int ni = 0; ni < 4; ni++) {
                const int col = n0 + wn + ni * 16 + lr;
                #pragma unroll
                for (int r = 0; r < 4; r++) {
                    const int rowg = m0 + wm + mi * 16 + lh * 4 + r;
                    pf[(size_t)rowg * N + col] = acc[mi][ni][r];
                }
            }
        return;
    }

    #pragma unroll
    for (int mi = 0; mi < 4; mi++) {
        #pragma unroll
        for (int ni = 0; ni < 4; ni++) {
            const int col = n0 + wn + ni * 16 + lr;
            const float bv = bias[col];
            #pragma unroll
            for (int r = 0; r < 4; r++) {
                const int rowg = m0 + wm + mi * 16 + lh * 4 + r;
                float v = acc[mi][ni][r] + bv;
                if (RES) v += res[(size_t)rowg * N + col];
                if (GELU) v = v * (1.0f / (1.0f + __expf(-1.702f * v)));
                if (OUTF) outF[(size_t)rowg * N + col] = v;
                if (OUTB) outB[(size_t)rowg * N + col] = f2bf(v);
            }
        }
    }
}

// ---------------------------------------------------------------------------
// Split-K reduce: out = sum(parts[0..3]) + bias + res   (f32, vectorized x4)
// ---------------------------------------------------------------------------
__global__ __launch_bounds__(256) void reduce4_kernel(
    const float* __restrict__ parts, const float* __restrict__ bias,
    const float* __restrict__ res, float* __restrict__ out, int N, size_t MN)
{
    const size_t i4 = ((size_t)blockIdx.x * 256 + threadIdx.x) * 4;
    if (i4 >= MN) return;
    float4v a = *reinterpret_cast<const float4v*>(parts + i4);
    a += *reinterpret_cast<const float4v*>(parts + MN + i4);
    a += *reinterpret_cast<const float4v*>(parts + 2 * MN + i4);
    a += *reinterpret_cast<const float4v*>(parts + 3 * MN + i4);
    a += *reinterpret_cast<const float4v*>(res + i4);
    const int col = (int)(i4 % N);
    a += *reinterpret_cast<const float4v*>(bias + col);
    *reinterpret_cast<float4v*>(out + i4) = a;
}

// ---------------------------------------------------------------------------
// RoPE + repack: qkv bf16 [S][3840] -> q bf16 [H][S][96] (pre-scaled 1/sqrt(80)),
// k bf16 [H][S][128] (pad 80->128, XOR-closed chunk space), v -> VT [H][80][S]
// ---------------------------------------------------------------------------
__global__ __launch_bounds__(256) void rope_kernel(
    const u16* __restrict__ qkv, const float* __restrict__ freqs,
    u16* __restrict__ qp, u16* __restrict__ kp, u16* __restrict__ vt)
{
    const int s = blockIdx.x, t = threadIdx.x;
    const float scale = 0.1118033988749895f;  // 1/sqrt(80)
    __shared__ float cs[40], sn[40];
    if (t < 40) {
        const float f = freqs[(size_t)s * 40 + t];
        cs[t] = cosf(f);
        sn[t] = sinf(f);
    }
    __syncthreads();
    const u16* row = qkv + (size_t)s * 3840;
    for (int i = t; i < 1280; i += 256) {
        const int h = i / 80, d = i % 80;
        const float c = cs[d >> 1], sv = sn[d >> 1];
        const float q0 = bf2f(row[i]);
        const float q1 = (d < 40) ? -bf2f(row[i + 40]) : bf2f(row[i - 40]);
        qp[((size_t)h * 3072 + s) * 96 + d] = f2bf((q0 * c + q1 * sv) * scale);
        const float k0 = bf2f(row[1280 + i]);
        const float k1 = (d < 40) ? -bf2f(row[1280 + i + 40]) : bf2f(row[1280 + i - 40]);
        kp[((size_t)h * 3072 + s) * 128 + d] = f2bf(k0 * c + k1 * sv);
        vt[((size_t)h * 80 + d) * 3072 + s] = row[2560 + i];
    }
    {
        const int h = t / 16, d = 80 + (t % 16);
        qp[((size_t)h * 3072 + s) * 96 + d] = 0;
    }
    for (int i = t; i < 768; i += 256) {
        const int h = i / 48, d = 80 + (i % 48);
        kp[((size_t)h * 3072 + s) * 128 + d] = 0;
    }
}

// ---------------------------------------------------------------------------
// Flash attention (R6 version, verified): swapped QK^T, K/V staged via
// global_load_lds with both-sides XOR swizzle, double-buffered.
// ---------------------------------------------------------------------------
__global__ __launch_bounds__(256) void attn_kernel(
    const u16* __restrict__ qp, const u16* __restrict__ kp,
    const u16* __restrict__ vt, u16* __restrict__ attn_out)
{
    const int tid = threadIdx.x, lane = tid & 63, wave = tid >> 6;
    const int w = xcd_swz(blockIdx.x, 768);
    const int qt = w & 15;
    const int h = (w >> 4) & 15;
    const int sq = w >> 8;
    const int lr = lane & 15, lh = lane >> 4;
    const int qrow = sq * 1024 + qt * 64 + wave * 16;

    __shared__ u16 Ks[2][64 * 128];
    __shared__ u16 Vs[2][80 * 64];
    __shared__ u16 P[4][16 * 72];

    bf16x8 aq[3];
    {
        const u16* qb = qp + ((size_t)h * 3072 + qrow + lr) * 96 + lh * 8;
        #pragma unroll
        for (int d0 = 0; d0 < 3; d0++)
            aq[d0] = *reinterpret_cast<const bf16x8*>(qb + d0 * 32);
    }

    float m = -1e30f, l = 0.f;
    f32x4 acc[5] = {};

    const u16* kseg = kp + ((size_t)h * 3072 + sq * 1024) * 128;
    const u16* vseg = vt + (size_t)h * 80 * 3072 + sq * 1024;

    const int krow_l = lane >> 4;
    const int kch    = lane & 15;
    const int vrow_l = lane >> 3;
    const int vch    = lane & 7;

    auto stageK = [&](int t, int buf) {
        #pragma unroll
        for (int s = 0; s < 4; s++) {
            const int seg = wave + s * 4;
            const int row = seg * 4 + krow_l;
            gld16(kseg + (size_t)(t * 64 + row) * 128 + ((kch ^ (row & 7)) * 8),
                  &Ks[buf][seg * 512]);
        }
    };
    auto stageV = [&](int t, int buf) {
        #pragma unroll
        for (int s = 0; s < 3; s++) {
            const int seg = wave + s * 4;
            if (seg < 10) {
                const int row = seg * 8 + vrow_l;
                gld16(vseg + (size_t)row * 3072 + t * 64 + ((vch ^ (row & 7)) * 8),
                      &Vs[buf][seg * 512]);
            }
        }
    };

    stageK(0, 0);
    stageV(0, 0);
    asm volatile("s_waitcnt vmcnt(0)" ::: "memory");
    __syncthreads();

    for (int t = 0; t < 16; t++) {
        const int cur = t & 1;
        if (t < 15) {
            stageK(t + 1, cur ^ 1);
            stageV(t + 1, cur ^ 1);
        }

        f32x4 sc[4] = {};
        #pragma unroll
        for (int c = 0; c < 4; c++) {
            #pragma unroll
            for (int d0 = 0; d0 < 3; d0++) {
                const int row = c * 16 + lr;
                const int rb = row * 256 + (((d0 * 4 + lh) ^ (row & 7)) << 4);
                bf16x8 kf = *reinterpret_cast<const bf16x8*>((const char*)Ks[cur] + rb);
                sc[c] = __builtin_amdgcn_mfma_f32_16x16x32_bf16(kf, aq[d0], sc[c], 0, 0, 0);
            }
        }

        float pmax = sc[0][0];
        #pragma unroll
        for (int c = 0; c < 4; c++)
            #pragma unroll
            for (int r = 0; r < 4; r++)
                pmax = fmaxf(pmax, sc[c][r]);
        pmax = fmaxf(pmax, __shfl_xor(pmax, 16));
        pmax = fmaxf(pmax, __shfl_xor(pmax, 32));

        if (!__all(pmax - m <= 8.0f)) {
            const float mn = fmaxf(m, pmax);
            const float fac = __expf(m - mn);
            m = mn;
            l *= fac;
            #pragma unroll
            for (int df = 0; df < 5; df++)
                #pragma unroll
                for (int r = 0; r < 4; r++)
                    acc[df][r] *= fac;
        }

        float p[4][4], rs = 0.f;
        #pragma unroll
        for (int c = 0; c < 4; c++)
            #pragma unroll
            for (int r = 0; r < 4; r++) {
                p[c][r] = __expf(sc[c][r] - m);
                rs += p[c][r];
            }
        rs += __shfl_xor(rs, 16);
        rs += __shfl_xor(rs, 32);
        l += rs;

        #pragma unroll
        for (int c = 0; c < 4; c++) {
            u16x4 pw;
            #pragma unroll
            for (int r = 0; r < 4; r++)
                pw[r] = f2bf(p[c][r]);
            *reinterpret_cast<u16x4*>((char*)P[wave] + lr * 144 + c * 32 + lh * 8) = pw;
        }
        asm volatile("s_waitcnt lgkmcnt(0)" ::: "memory");

        #pragma unroll
        for (int ks = 0; ks < 2; ks++) {
            bf16x8 pa = *reinterpret_cast<const bf16x8*>(
                (const char*)P[wave] + lr * 144 + ks * 64 + lh * 16);
            #pragma unroll
            for (int df = 0; df < 5; df++) {
                const int row = df * 16 + lr;
                const int vb = row * 128 + (((ks * 4 + lh) ^ (row & 7)) << 4);
                bf16x8 vf = *reinterpret_cast<const bf16x8*>((const char*)Vs[cur] + vb);
                acc[df] = __builtin_amdgcn_mfma_f32_16x16x32_bf16(vf, pa, acc[df], 0, 0, 0);
            }
        }

        asm volatile("s_waitcnt vmcnt(0)" ::: "memory");
        __syncthreads();
    }

    const float invl = 1.0f / l;
    u16* orow = attn_out + (size_t)(qrow + lr) * 1280 + h * 80;
    #pragma unroll
    for (int df = 0; df < 5; df++) {
        u16x4 o;
        #pragma unroll
        for (int r = 0; r < 4; r++)
            o[r] = f2bf(acc[df][r] * invl);
        *reinterpret_cast<u16x4*>(orow + df * 16 + lh * 4) = o;
    }
}

// ---------------------------------------------------------------------------
extern "C" void kernel_launch(void* const* d_in, const int* in_sizes, int n_in,
                              void* d_out, int out_size, void* d_ws, size_t ws_size,
                              hipStream_t stream) {
    const float* hidden = (const float*)d_in[0];
    const float* rot    = (const float*)d_in[1];
    const float* ln1s   = (const float*)d_in[2];
    const float* ln1b   = (const float*)d_in[3];
    const float* ln2s   = (const float*)d_in[4];
    const float* ln2b   = (const float*)d_in[5];
    const float* qkvw   = (const float*)d_in[6];
    const float* qkvb   = (const float*)d_in[7];
    const float* projw  = (const float*)d_in[8];
    const float* projb  = (const float*)d_in[9];
    const float* fc1w   = (const float*)d_in[10];
    const float* fc1b   = (const float*)d_in[11];
    const float* fc2w   = (const float*)d_in[12];
    const float* fc2b   = (const float*)d_in[13];
    // cu_seqlens fixed [0,1024,2048,3072] -> 3 segments of 1024.
    float* out = (float*)d_out;

    char* p = (char*)d_ws;
    auto alloc = [&](size_t n) { char* r = p; p += (n + 255) & ~(size_t)255; return r; };
    u16* qkvwT  = (u16*)alloc((size_t)3840 * 1280 * 2);
    u16* projwT = (u16*)alloc((size_t)1280 * 1280 * 2);
    u16* fc1wT  = (u16*)alloc((size_t)5120 * 1280 * 2);
    u16* fc2wT  = (u16*)alloc((size_t)1280 * 5120 * 2);
    u16* hbuf   = (u16*)alloc((size_t)3072 * 1280 * 2);        // reused as h2
    u16* qkvbf  = (u16*)alloc((size_t)3072 * 5120 * 2);        // qkv bf16; reused as mlp1
    u16* attnb  = (u16*)alloc((size_t)3072 * 1280 * 2);
    float* xmid = (float*)alloc((size_t)3072 * 1280 * 4);
    // union region: {qp,kp,vt} (~30 MB, dead after attn) / split-K parts (62.9 MB)
    float* parts = (float*)alloc((size_t)4 * 3072 * 1280 * 4);
    u16* qp2 = (u16*)parts;                                    // [16][3072][96]
    u16* kp2 = qp2 + (size_t)16 * 3072 * 96;                   // [16][3072][128]
    u16* vt2 = kp2 + (size_t)16 * 3072 * 128;                  // [16][80][3072]
    u16* h2   = hbuf;
    u16* mlp1 = qkvbf;
    const size_t MN = (size_t)3072 * 1280;

    transpose_kernel<<<dim3(3840 / 64, 1280 / 64), 256, 0, stream>>>(qkvw, qkvwT, 1280, 3840);
    transpose_kernel<<<dim3(1280 / 64, 1280 / 64), 256, 0, stream>>>(projw, projwT, 1280, 1280);
    transpose_kernel<<<dim3(5120 / 64, 1280 / 64), 256, 0, stream>>>(fc1w, fc1wT, 1280, 5120);
    transpose_kernel<<<dim3(1280 / 64, 5120 / 64), 256, 0, stream>>>(fc2w, fc2wT, 5120, 1280);

    ln_kernel<<<3072, 256, 0, stream>>>(hidden, ln1s, ln1b, hbuf);
    // qkv = h @ qkv_w + b  (bf16 out), 256^2 pipeline
    gemm256_kernel<0, 1, 1><<<dim3(15, 12), 512, 0, stream>>>(
        hbuf, qkvwT, qkvb, nullptr, qkvbf, 3072, 3840, 1280);
    rope_kernel<<<3072, 256, 0, stream>>>(qkvbf, rot, qp2, kp2, vt2);
    attn_kernel<<<768, 256, 0, stream>>>(qp2, kp2, vt2, attnb);
    // proj: split-K x4 (128^2) -> parts; reduce adds bias + hidden -> xmid
    gemm_kernel<0, 0, 1, 0, 4><<<dim3(10, 24, 4), 256, 0, stream>>>(
        attnb, projwT, projb, nullptr, parts, nullptr, 3072, 1280, 1280);
    reduce4_kernel<<<(int)(MN / 4 / 256), 256, 0, stream>>>(parts, projb, hidden, xmid, 1280, MN);
    ln_kernel<<<3072, 256, 0, stream>>>(xmid, ln2s, ln2b, h2);
    // mlp1 = gelu(h2 @ fc1_w + b)  (bf16), 256^2 pipeline
    gemm256_kernel<1, 1, 1><<<dim3(20, 12), 512, 0, stream>>>(
        h2, fc1wT, fc1b, nullptr, mlp1, 3072, 5120, 1280);
    // fc2: 256^2 split-K x4 -> parts; reduce adds bias + xmid -> out
    gemm256_kernel<0, 0, 4><<<dim3(5, 12, 4), 512, 0, stream>>>(
        mlp1, fc2wT, fc2b, parts, nullptr, 3072, 1280, 5120);
    reduce4_kernel<<<(int)(MN / 4 / 256), 256, 0, stream>>>(parts, fc2b, xmid, out, 1280, MN);
}